// Round 19
// baseline (56.652 us; speedup 1.0000x reference)
//
#include <hip/hip_runtime.h>

#define GROUPS 196

// Lane mapping: lane = q*16 + py (q = px-quad = DPP-row index, py = pixel row).
// Vertical (py+-1) = lane+-1 = DPP row_shr/row_shl, bound_ctrl zero-fill lands
// exactly on py=0/15 tile edges (mask-free zero-pad). Horizontal cross-quad
// (q+-1) = lane+-16 via ds_bpermute + MULTIPLY masks. All cross-lane ops are
// UNCONDITIONAL (EXEC=all-64; R12-R14 failed from DPP under exec-masked
// selects). bperm/DPP commute (disjoint axes); q-masks are DPP-row-coherent.
__device__ __forceinline__ float dppL(float v) {   // lane l gets v of lane l-1
    return __int_as_float(__builtin_amdgcn_update_dpp(
        __float_as_int(v), __float_as_int(v), 0x111, 0xF, 0xF, true));
}
__device__ __forceinline__ float dppR(float v) {   // lane l gets v of lane l+1
    return __int_as_float(__builtin_amdgcn_update_dpp(
        __float_as_int(v), __float_as_int(v), 0x101, 0xF, 0xF, true));
}
__device__ __forceinline__ float bperm(int addr, float v) {
    return __int_as_float(__builtin_amdgcn_ds_bpermute(addr, __float_as_int(v)));
}
__device__ __forceinline__ float qgelu(float v) {  // exact: unbounded domain
    return v * __builtin_amdgcn_rcpf(1.0f + __expf(-1.702f * v));
}
// p * sigmoid(1.702 p) on [0,1]; deg-3 poly, |err| ~1e-3 (validated R17).
__device__ __forceinline__ float qgelu01(float p) {
    return p * fmaf(p, fmaf(p, -0.11333f, 0.46195f), 0.49805f);
}

// One WAVE per (g,b) tile, 4 px/lane. Zero LDS memory / fences / barriers.
// launch_bounds(256, 8): pin VGPR <= 64 so 8 waves/SIMD are resident (R15-R18
// plateaued at ~30.6us from 4-wave occupancy; conv is streamed per (ic,ky) and
// the tail per-oc to keep the live set ~45 regs).
__global__ __launch_bounds__(256, 8) void convpass_fused(
    const float* __restrict__ x,
    const float* __restrict__ conv_w,
    const float* __restrict__ conv_b,
    const float* __restrict__ centers,
    const float* __restrict__ widths,
    const float* __restrict__ down_w,
    const float* __restrict__ down_b,
    float* __restrict__ out)
{
    const int tid = threadIdx.x;
    const int l  = tid & 63;
    const int wv = tid >> 6;
    const int g  = blockIdx.x * 4 + wv;      // grid.x = 49 -> g in [0,196)
    const int b  = blockIdx.y;
    const int q  = l >> 4;                   // px quad 0..3 (DPP row)
    const int py = l & 15;                   // pixel row 0..15
    const float mL = (q > 0) ? 1.f : 0.f;    // cross-quad masks (MULTIPLY only)
    const float mR = (q < 3) ? 1.f : 0.f;
    const int aL = ((l - 16) & 63) << 2;     // bpermute byte addr: lane-16
    const int aR = ((l + 16) & 63) << 2;     // lane+16

    // wave-uniform group index -> scalar loads for all params
    const int sg = __builtin_amdgcn_readfirstlane(g);
    const float* cw  = conv_w  + sg * 81;
    const float* cen = centers + sg * 12;
    const float* wid = widths  + sg * 12;
    const float* dwp = down_w  + sg * 36;

    // ---- load own 4 px (row py, quad q) of 3 channels: coalesced dwordx4 ----
    const int tok = b * 197 + g + 1;
    const float4* xin4 = (const float4*)x + tok * 192;
    const int fo = py * 4 + q;               // float4 index in a 64-float4 plane
    float4 A0 = xin4[fo];
    float4 A1 = xin4[64 + fo];
    float4 A2 = xin4[128 + fo];

    // ---- grouped 3x3 conv, STREAMED per (ic, ky): rows derived from A[ic]
    //      by DPP at use, edge columns from one bperm pair per channel ----
    float acc[3][4];
    {
        const float cb0 = conv_b[sg*3+0], cb1 = conv_b[sg*3+1], cb2 = conv_b[sg*3+2];
        #pragma unroll
        for (int j = 0; j < 4; ++j) { acc[0][j] = cb0; acc[1][j] = cb1; acc[2][j] = cb2; }
    }
    #pragma unroll
    for (int ic = 0; ic < 3; ++ic) {
        const float4 a = (ic == 0) ? A0 : (ic == 1) ? A1 : A2;
        const float eL = bperm(aL, a.w) * mL;   // (py, q-1).px3, center row
        const float eR = bperm(aR, a.x) * mR;   // (py, q+1).px0
        #pragma unroll
        for (int ky = 0; ky < 3; ++ky) {
            float4 v; float vl, vr;
            if (ky == 0)      { v = make_float4(dppL(a.x), dppL(a.y), dppL(a.z), dppL(a.w));
                                vl = dppL(eL); vr = dppL(eR); }
            else if (ky == 1) { v = a; vl = eL; vr = eR; }
            else              { v = make_float4(dppR(a.x), dppR(a.y), dppR(a.z), dppR(a.w));
                                vl = dppR(eL); vr = dppR(eR); }
            #pragma unroll
            for (int oc = 0; oc < 3; ++oc) {
                const float w0 = cw[oc*27 + ic*9 + ky*3 + 0];
                const float w1 = cw[oc*27 + ic*9 + ky*3 + 1];
                const float w2 = cw[oc*27 + ic*9 + ky*3 + 2];
                acc[oc][0] = fmaf(vl,  w0, fmaf(v.x, w1, fmaf(v.y, w2, acc[oc][0])));
                acc[oc][1] = fmaf(v.x, w0, fmaf(v.y, w1, fmaf(v.z, w2, acc[oc][1])));
                acc[oc][2] = fmaf(v.y, w0, fmaf(v.z, w1, fmaf(v.w, w2, acc[oc][2])));
                acc[oc][3] = fmaf(v.z, w0, fmaf(v.w, w1, fmaf(vr,  w2, acc[oc][3])));
            }
        }
    }

    // exclude-pad reciprocals 1/(vx*vy); px edges: px==0 (q0,j0), px==15 (q3,j3)
    const bool  vy2 = (py == 0) | (py == 15);
    const float rE = vy2 ? 0.25f     : (1.f/6.f);
    const float rM = vy2 ? (1.f/6.f) : (1.f/9.f);
    const float rc0 = (q == 0) ? rE : rM;
    const float rc3 = (q == 3) ? rE : rM;

    float o[3][4];
    {
        const float db0 = down_b[sg*3+0], db1 = down_b[sg*3+1], db2 = down_b[sg*3+2];
        #pragma unroll
        for (int j = 0; j < 4; ++j) { o[0][j] = db0; o[1][j] = db1; o[2][j] = db2; }
    }

    // ---- per-oc: gelu -> hist -> horiz 3-sum -> vert 3-sum (DPP) -> proj ----
    // widths>0, |.|>=0 => t_k >= 1: relu and +1e-5 are no-ops (R10+).
    // bin3 via sum-to-1 identity (R11+).
    #pragma unroll
    for (int oc = 0; oc < 3; ++oc) {
        float hj[3][4];
        #pragma unroll
        for (int j = 0; j < 4; ++j) {
            const float y = qgelu(acc[oc][j]);
            const float t0 = fmaf(wid[oc*4+0], fabsf(y + cen[oc*4+0]), 1.0f);
            const float t1 = fmaf(wid[oc*4+1], fabsf(y + cen[oc*4+1]), 1.0f);
            const float t2 = fmaf(wid[oc*4+2], fabsf(y + cen[oc*4+2]), 1.0f);
            const float t3 = fmaf(wid[oc*4+3], fabsf(y + cen[oc*4+3]), 1.0f);
            const float inv = __builtin_amdgcn_rcpf((t0 + t1) + (t2 + t3));
            hj[0][j] = t0 * inv; hj[1][j] = t1 * inv; hj[2][j] = t2 * inv;
        }
        float rs[3][4];
        #pragma unroll
        for (int k = 0; k < 3; ++k) {
            const float lh = bperm(aL, hj[k][3]);   // unconditional crossbar
            const float rh = bperm(aR, hj[k][0]);
            const float s01 = hj[k][0] + hj[k][1];
            const float s23 = hj[k][2] + hj[k][3];
            rs[k][0] = fmaf(mL, lh, s01);
            rs[k][1] = s01 + hj[k][2];
            rs[k][2] = hj[k][1] + s23;
            rs[k][3] = fmaf(mR, rh, s23);
        }
        #pragma unroll
        for (int j = 0; j < 4; ++j) {
            const float rcj = (j == 0) ? rc0 : (j == 3) ? rc3 : rM;
            const float v0 = rs[0][j] + dppL(rs[0][j]) + dppR(rs[0][j]);
            const float v1 = rs[1][j] + dppL(rs[1][j]) + dppR(rs[1][j]);
            const float v2 = rs[2][j] + dppL(rs[2][j]) + dppR(rs[2][j]);
            const float p0 = v0 * rcj;
            const float p1 = v1 * rcj;
            const float p2 = v2 * rcj;
            const float p3 = 1.0f - p0 - p1 - p2;
            const float u0 = qgelu01(p0);
            const float u1 = qgelu01(p1);
            const float u2 = qgelu01(p2);
            const float u3 = qgelu01(p3);
            const int i = oc * 4;
            o[0][j] = fmaf(u0, dwp[i],    fmaf(u1, dwp[i+1],    fmaf(u2, dwp[i+2],    fmaf(u3, dwp[i+3],    o[0][j]))));
            o[1][j] = fmaf(u0, dwp[12+i], fmaf(u1, dwp[12+i+1], fmaf(u2, dwp[12+i+2], fmaf(u3, dwp[12+i+3], o[1][j]))));
            o[2][j] = fmaf(u0, dwp[24+i], fmaf(u1, dwp[24+i+1], fmaf(u2, dwp[24+i+2], fmaf(u3, dwp[24+i+3], o[2][j]))));
        }
    }

    // ---- vectorized output stores (wave covers each 1KB span completely) ----
    float4* op4 = (float4*)out + tok * 192;
    op4[fo]       = make_float4(o[0][0], o[0][1], o[0][2], o[0][3]);
    op4[64 + fo]  = make_float4(o[1][0], o[1][1], o[1][2], o[1][3]);
    op4[128 + fo] = make_float4(o[2][0], o[2][1], o[2][2], o[2][3]);

    // ---- CLS pass-through: wave g==0 of each batch (wave-uniform branch) ----
    if (g == 0) {
        const float4* xc = (const float4*)x + b * 197 * 192;
        float4* oc4 = (float4*)out + b * 197 * 192;
        oc4[l]       = xc[l];
        oc4[64 + l]  = xc[64 + l];
        oc4[128 + l] = xc[128 + l];
    }
}

extern "C" void kernel_launch(void* const* d_in, const int* in_sizes, int n_in,
                              void* d_out, int out_size, void* d_ws, size_t ws_size,
                              hipStream_t stream) {
    const float* x       = (const float*)d_in[0];
    const float* conv_w  = (const float*)d_in[1];
    const float* conv_b  = (const float*)d_in[2];
    const float* centers = (const float*)d_in[3];
    const float* widths  = (const float*)d_in[4];
    const float* down_w  = (const float*)d_in[5];
    const float* down_b  = (const float*)d_in[6];
    float* out = (float*)d_out;

    const int B = in_sizes[0] / (197 * 768);

    dim3 grid(GROUPS / 4, B);   // 49 x B blocks, 4 waves/block, 1 tile/wave
    convpass_fused<<<grid, 256, 0, stream>>>(x, conv_w, conv_b, centers, widths,
                                             down_w, down_b, out);
}

// Round 20
// 30.125 us; speedup vs baseline: 1.8806x; 1.8806x over previous
//
#include <hip/hip_runtime.h>

#define GROUPS 196

typedef _Float16 half2v __attribute__((ext_vector_type(2)));

// ---- cross-lane helpers (UNCONDITIONAL use only; EXEC = all 64 lanes).
// Lane mapping: lane = q*16 + py. Vertical (py+-1) = lane+-1 = DPP
// row_shr/row_shl, bound_ctrl zero-fill lands exactly on py=0/15 tile edges.
// Horizontal cross-quad (q+-1) = lane+-16 via ds_bpermute + MULTIPLY masks.
__device__ __forceinline__ int dppLi(int v) {
    return __builtin_amdgcn_update_dpp(v, v, 0x111, 0xF, 0xF, true);
}
__device__ __forceinline__ int dppRi(int v) {
    return __builtin_amdgcn_update_dpp(v, v, 0x101, 0xF, 0xF, true);
}
__device__ __forceinline__ float dppL(float v) {
    return __int_as_float(dppLi(__float_as_int(v)));
}
__device__ __forceinline__ float dppR(float v) {
    return __int_as_float(dppRi(__float_as_int(v)));
}
__device__ __forceinline__ half2v dppL2(half2v v) {
    return __builtin_bit_cast(half2v, dppLi(__builtin_bit_cast(int, v)));
}
__device__ __forceinline__ half2v dppR2(half2v v) {
    return __builtin_bit_cast(half2v, dppRi(__builtin_bit_cast(int, v)));
}
__device__ __forceinline__ float bperm(int addr, float v) {
    return __int_as_float(__builtin_amdgcn_ds_bpermute(addr, __float_as_int(v)));
}
__device__ __forceinline__ half2v bperm2(int addr, half2v v) {
    return __builtin_bit_cast(half2v,
        __builtin_amdgcn_ds_bpermute(addr, __builtin_bit_cast(int, v)));
}
__device__ __forceinline__ half2v h2pack(float a, float b) {  // v_cvt_pkrtz
    return __builtin_bit_cast(half2v, __builtin_amdgcn_cvt_pkrtz(a, b));
}
__device__ __forceinline__ half2v h2abs(half2v a) {
    const int i = __builtin_bit_cast(int, a) & 0x7FFF7FFF;
    return __builtin_bit_cast(half2v, i);
}
__device__ __forceinline__ float fdot2(half2v a, half2v b, float c) {
    return __builtin_amdgcn_fdot2(a, b, c, false);   // v_dot2_f32_f16
}
__device__ __forceinline__ float qgelu(float v) {  // exact: unbounded domain
    return v * __builtin_amdgcn_rcpf(1.0f + __expf(-1.702f * v));
}

// One WAVE per (g,b) tile, 4 px/lane (px = q*4+j, row py).
// Conv + quick_gelu in f32 (exact); histogram -> pool -> poly-gelu -> 12->3
// projection in packed f16 (bin-pairs per half2; j stays register axis so
// horizontal logic is unchanged and vertical DPP moves both bins at once).
// All 4 bins kept (no p3 identity needed). Zero LDS / fences / barriers.
__global__ __launch_bounds__(256) void convpass_fused(
    const float* __restrict__ x,
    const float* __restrict__ conv_w,
    const float* __restrict__ conv_b,
    const float* __restrict__ centers,
    const float* __restrict__ widths,
    const float* __restrict__ down_w,
    const float* __restrict__ down_b,
    float* __restrict__ out)
{
    const int tid = threadIdx.x;
    const int l  = tid & 63;
    const int wv = tid >> 6;
    const int g  = blockIdx.x * 4 + wv;      // grid.x = 49 -> g in [0,196)
    const int b  = blockIdx.y;
    const int q  = l >> 4;                   // px quad 0..3 (DPP row)
    const int py = l & 15;                   // pixel row 0..15
    const float mL = (q > 0) ? 1.f : 0.f;    // cross-quad masks (MULTIPLY only)
    const float mR = (q < 3) ? 1.f : 0.f;
    const int aL = ((l - 16) & 63) << 2;     // bpermute byte addr: lane-16
    const int aR = ((l + 16) & 63) << 2;     // lane+16

    // wave-uniform group index -> scalar loads for all params
    const int sg = __builtin_amdgcn_readfirstlane(g);
    const float* cw  = conv_w  + sg * 81;
    const float* cen = centers + sg * 12;
    const float* wid = widths  + sg * 12;
    const float* dwp = down_w  + sg * 36;

    // ---- load own 4 px of 3 channels: coalesced dwordx4 ----
    const int tok = b * 197 + g + 1;
    const float4* xin4 = (const float4*)x + tok * 192;
    const int fo = py * 4 + q;
    const float4 A0 = xin4[fo];
    const float4 A1 = xin4[64 + fo];
    const float4 A2 = xin4[128 + fo];

    // ---- rows py-1 / py / py+1 per channel via mask-free DPP ----
    float4 V[3][3];
    V[0][1] = A0; V[1][1] = A1; V[2][1] = A2;
    #pragma unroll
    for (int ic = 0; ic < 3; ++ic) {
        const float4 a = V[ic][1];
        V[ic][0] = make_float4(dppL(a.x), dppL(a.y), dppL(a.z), dppL(a.w));
        V[ic][2] = make_float4(dppR(a.x), dppR(a.y), dppR(a.z), dppR(a.w));
    }
    // cross-quad edge columns: one bperm pair per channel at center row,
    // masked once (DPP-row-coherent), shifted vertically in-register
    float L[3][3], R[3][3];
    #pragma unroll
    for (int ic = 0; ic < 3; ++ic) {
        const float eL = bperm(aL, V[ic][1].w) * mL;
        const float eR = bperm(aR, V[ic][1].x) * mR;
        L[ic][0] = dppL(eL); L[ic][1] = eL; L[ic][2] = dppR(eL);
        R[ic][0] = dppL(eR); R[ic][1] = eR; R[ic][2] = dppR(eR);
    }

    // ---- grouped 3x3 conv (f32, all in-register) ----
    float acc[3][4];
    {
        const float cb0 = conv_b[sg*3+0], cb1 = conv_b[sg*3+1], cb2 = conv_b[sg*3+2];
        #pragma unroll
        for (int j = 0; j < 4; ++j) { acc[0][j] = cb0; acc[1][j] = cb1; acc[2][j] = cb2; }
    }
    #pragma unroll
    for (int oc = 0; oc < 3; ++oc) {
        #pragma unroll
        for (int ic = 0; ic < 3; ++ic) {
            #pragma unroll
            for (int r = 0; r < 3; ++r) {
                const float w0 = cw[oc*27 + ic*9 + r*3 + 0];
                const float w1 = cw[oc*27 + ic*9 + r*3 + 1];
                const float w2 = cw[oc*27 + ic*9 + r*3 + 2];
                const float4 v = V[ic][r];
                acc[oc][0] = fmaf(L[ic][r], w0, fmaf(v.x, w1, fmaf(v.y, w2, acc[oc][0])));
                acc[oc][1] = fmaf(v.x,      w0, fmaf(v.y, w1, fmaf(v.z, w2, acc[oc][1])));
                acc[oc][2] = fmaf(v.y,      w0, fmaf(v.z, w1, fmaf(v.w, w2, acc[oc][2])));
                acc[oc][3] = fmaf(v.z,      w0, fmaf(v.w, w1, fmaf(R[ic][r], w2, acc[oc][3])));
            }
        }
    }

    // ---- pack per-group params to f16 pairs (once per wave) ----
    half2v cen01[3], cen23[3], wid01[3], wid23[3];
    half2v dw01[3][3], dw23[3][3];   // [m][oc]
    #pragma unroll
    for (int oc = 0; oc < 3; ++oc) {
        cen01[oc] = h2pack(cen[oc*4+0], cen[oc*4+1]);
        cen23[oc] = h2pack(cen[oc*4+2], cen[oc*4+3]);
        wid01[oc] = h2pack(wid[oc*4+0], wid[oc*4+1]);
        wid23[oc] = h2pack(wid[oc*4+2], wid[oc*4+3]);
        #pragma unroll
        for (int m = 0; m < 3; ++m) {
            dw01[m][oc] = h2pack(dwp[m*12+oc*4+0], dwp[m*12+oc*4+1]);
            dw23[m][oc] = h2pack(dwp[m*12+oc*4+2], dwp[m*12+oc*4+3]);
        }
    }
    const half2v one2 = h2pack(1.f, 1.f);
    const half2v mL2 = h2pack(mL, mL);
    const half2v mR2 = h2pack(mR, mR);
    // poly coeffs (deg-3 qgelu01 on [0,1], validated R17)
    const half2v C0 = h2pack(0.49805f, 0.49805f);
    const half2v C1 = h2pack(0.46195f, 0.46195f);
    const half2v C2 = h2pack(-0.11333f, -0.11333f);

    // exclude-pad reciprocals, packed per j
    const bool  vy2 = (py == 0) | (py == 15);
    const float rE = vy2 ? 0.25f     : (1.f/6.f);
    const float rM = vy2 ? (1.f/6.f) : (1.f/9.f);
    half2v rc2[4];
    rc2[0] = h2pack((q == 0) ? rE : rM, (q == 0) ? rE : rM);
    rc2[1] = h2pack(rM, rM);
    rc2[2] = rc2[1];
    rc2[3] = h2pack((q == 3) ? rE : rM, (q == 3) ? rE : rM);

    float o[3][4];
    {
        const float db0 = down_b[sg*3+0], db1 = down_b[sg*3+1], db2 = down_b[sg*3+2];
        #pragma unroll
        for (int j = 0; j < 4; ++j) { o[0][j] = db0; o[1][j] = db1; o[2][j] = db2; }
    }

    // ---- per-oc tail, packed f16 by bin-pairs ----
    // widths>0, |.|>=0 => t_k >= 1: relu and +1e-5 are no-ops (R10+).
    #pragma unroll
    for (int oc = 0; oc < 3; ++oc) {
        half2v h01[4], h23[4];
        #pragma unroll
        for (int j = 0; j < 4; ++j) {
            const float y = qgelu(acc[oc][j]);
            const half2v y2 = h2pack(y, y);
            const half2v t01 = wid01[oc] * h2abs(y2 + cen01[oc]) + one2;
            const half2v t23 = wid23[oc] * h2abs(y2 + cen23[oc]) + one2;
            const float sum = fdot2(t01, one2, fdot2(t23, one2, 0.f));
            const float inv = __builtin_amdgcn_rcpf(sum);
            const half2v inv2 = h2pack(inv, inv);
            h01[j] = t01 * inv2;
            h23[j] = t23 * inv2;
        }
        // horizontal 3-sum; cross-quad edges via bpermute (packed), mask-fma
        half2v rs01[4], rs23[4];
        {
            const half2v lh01 = bperm2(aL, h01[3]);
            const half2v lh23 = bperm2(aL, h23[3]);
            const half2v rh01 = bperm2(aR, h01[0]);
            const half2v rh23 = bperm2(aR, h23[0]);
            const half2v sa01 = h01[0] + h01[1], sb01 = h01[2] + h01[3];
            const half2v sa23 = h23[0] + h23[1], sb23 = h23[2] + h23[3];
            rs01[0] = mL2 * lh01 + sa01;
            rs01[1] = sa01 + h01[2];
            rs01[2] = h01[1] + sb01;
            rs01[3] = mR2 * rh01 + sb01;
            rs23[0] = mL2 * lh23 + sa23;
            rs23[1] = sa23 + h23[2];
            rs23[2] = h23[1] + sb23;
            rs23[3] = mR2 * rh23 + sb23;
        }
        // vertical 3-sum (mask-free DPP, both bins per op) + avg + poly + proj
        #pragma unroll
        for (int j = 0; j < 4; ++j) {
            const half2v v01 = rs01[j] + dppL2(rs01[j]) + dppR2(rs01[j]);
            const half2v v23 = rs23[j] + dppL2(rs23[j]) + dppR2(rs23[j]);
            const half2v p01 = v01 * rc2[j];
            const half2v p23 = v23 * rc2[j];
            const half2v u01 = p01 * (C0 + p01 * (C1 + p01 * C2));
            const half2v u23 = p23 * (C0 + p23 * (C1 + p23 * C2));
            o[0][j] = fdot2(u01, dw01[0][oc], fdot2(u23, dw23[0][oc], o[0][j]));
            o[1][j] = fdot2(u01, dw01[1][oc], fdot2(u23, dw23[1][oc], o[1][j]));
            o[2][j] = fdot2(u01, dw01[2][oc], fdot2(u23, dw23[2][oc], o[2][j]));
        }
    }

    // ---- vectorized output stores ----
    float4* op4 = (float4*)out + tok * 192;
    op4[fo]       = make_float4(o[0][0], o[0][1], o[0][2], o[0][3]);
    op4[64 + fo]  = make_float4(o[1][0], o[1][1], o[1][2], o[1][3]);
    op4[128 + fo] = make_float4(o[2][0], o[2][1], o[2][2], o[2][3]);

    // ---- CLS pass-through: wave g==0 of each batch (wave-uniform branch) ----
    if (g == 0) {
        const float4* xc = (const float4*)x + b * 197 * 192;
        float4* oc4 = (float4*)out + b * 197 * 192;
        oc4[l]       = xc[l];
        oc4[64 + l]  = xc[64 + l];
        oc4[128 + l] = xc[128 + l];
    }
}

extern "C" void kernel_launch(void* const* d_in, const int* in_sizes, int n_in,
                              void* d_out, int out_size, void* d_ws, size_t ws_size,
                              hipStream_t stream) {
    const float* x       = (const float*)d_in[0];
    const float* conv_w  = (const float*)d_in[1];
    const float* conv_b  = (const float*)d_in[2];
    const float* centers = (const float*)d_in[3];
    const float* widths  = (const float*)d_in[4];
    const float* down_w  = (const float*)d_in[5];
    const float* down_b  = (const float*)d_in[6];
    float* out = (float*)d_out;

    const int B = in_sizes[0] / (197 * 768);

    dim3 grid(GROUPS / 4, B);   // 49 x B blocks, 4 waves/block, 1 tile/wave
    convpass_fused<<<grid, 256, 0, stream>>>(x, conv_w, conv_b, centers, widths,
                                             down_w, down_b, out);
}